// Round 2
// baseline (180.918 us; speedup 1.0000x reference)
//
#include <hip/hip_runtime.h>
#include <cstdint>
#include <math.h>

#define HW 224
#define NPIX (HW*HW)          // 50176 = 784*64
#define BATCH 32
#define KP 64
#define PS 16
#define NCLS 1000
#define TKW 112               // 64-candidate runs per image (28 bands x 4 waves)
#define FC1_KS 16             // fc1 K-split
#define FC1_LS 69             // padded LDS stride for fc1 tiles

// ---------------------------------------------------------------------------
// Top-64 helpers: in-wave bitonic selection on packed 64-bit keys.
// key = monotone(value) << 32 | ~index  -> order == (value desc, index asc).
// ---------------------------------------------------------------------------
__device__ __forceinline__ uint64_t tk_pack(float v, int idx) {
    uint32_t u = __float_as_uint(v);
    u = (u & 0x80000000u) ? ~u : (u | 0x80000000u);
    return ((uint64_t)u << 32) | (uint32_t)(~idx);
}

__device__ __forceinline__ uint64_t tk_sort_asc(uint64_t k, int lane) {
    #pragma unroll
    for (int size = 2; size <= 64; size <<= 1) {
        #pragma unroll
        for (int stride = size >> 1; stride >= 1; stride >>= 1) {
            uint64_t o = __shfl_xor(k, stride, 64);
            bool up = ((lane & size) == 0);
            bool keepmax = (((lane & stride) != 0) == up);
            k = keepmax ? (k > o ? k : o) : (k < o ? k : o);
        }
    }
    return k;
}

__device__ __forceinline__ uint64_t tk_clean_desc(uint64_t k, int lane) {
    #pragma unroll
    for (int stride = 32; stride >= 1; stride >>= 1) {
        uint64_t o = __shfl_xor(k, stride, 64);
        bool keepmax = ((lane & stride) == 0);
        k = keepmax ? (k > o ? k : o) : (k < o ? k : o);
    }
    return k;
}

// ---------------------------------------------------------------------------
// K1: FUSED Harris + per-band top-64. One block per (8-row band, image).
// ---------------------------------------------------------------------------
__global__ __launch_bounds__(256) void k_harris_topk(const float* __restrict__ x,
                                                     uint64_t* __restrict__ cand) {
    const int r = blockIdx.x, b = blockIdx.y;
    const int tid = threadIdx.x;
    const int row0 = r * 8;
    __shared__ float G[12][228];
    __shared__ float DXs[10][228];
    __shared__ float DYs[10][228];
    __shared__ float RB[1792];
    const float* xb = x + (size_t)b * 3 * NPIX;

    // grayscale stage (stored at col+1; cols 0 and 225 are zero pads)
    for (int l = tid; l < 12 * 224; l += 256) {
        int gr = l / 224, gc = l % 224;
        int gy = row0 - 2 + gr;
        float v = 0.f;
        if (gy >= 0 && gy < HW) {
            int o = gy * HW + gc;
            v = (xb[o] + xb[NPIX + o] + xb[2 * NPIX + o]) / 3.0f;
        }
        G[gr][gc + 1] = v;
    }
    if (tid < 12) { G[tid][0] = 0.f; G[tid][225] = 0.f; }
    if (tid < 10) { DXs[tid][0] = 0.f; DXs[tid][225] = 0.f;
                    DYs[tid][0] = 0.f; DYs[tid][225] = 0.f; }
    __syncthreads();

    // Sobel dx/dy (zero outside image)
    for (int l = tid; l < 10 * 224; l += 256) {
        int dr = l / 224, dc = l % 224;
        int ay = row0 - 1 + dr;
        float dxv = 0.f, dyv = 0.f;
        if (ay >= 0 && ay < HW) {
            dxv = (G[dr][dc + 2] - G[dr][dc]) + (G[dr + 1][dc + 2] - G[dr + 1][dc]) +
                  (G[dr + 2][dc + 2] - G[dr + 2][dc]);
            dyv = (G[dr + 2][dc] + G[dr + 2][dc + 1] + G[dr + 2][dc + 2]) -
                  (G[dr][dc] + G[dr][dc + 1] + G[dr][dc + 2]);
        }
        DXs[dr][dc + 1] = dxv;
        DYs[dr][dc + 1] = dyv;
    }
    __syncthreads();

    // Harris response for band rows row0..row0+7 (masked -> exact 0)
    for (int l = tid; l < 1792; l += 256) {
        int rr = l / 224, c = l % 224;
        int gy = row0 + rr;
        float outv = 0.f;
        if (gy >= PS && gy < HW - PS && c >= PS && c < HW - PS) {
            const float gw[3][3] = {{1.f/16.f, 2.f/16.f, 1.f/16.f},
                                    {2.f/16.f, 4.f/16.f, 2.f/16.f},
                                    {1.f/16.f, 2.f/16.f, 1.f/16.f}};
            float sxx = 0.f, syy = 0.f, sxy = 0.f;
            #pragma unroll
            for (int u = 0; u < 3; u++)
                #pragma unroll
                for (int v = 0; v < 3; v++) {
                    float dv = DXs[rr + u][c + v];
                    float ev = DYs[rr + u][c + v];
                    float w = gw[u][v];
                    sxx += w * dv * dv;
                    syy += w * ev * ev;
                    sxy += w * dv * ev;
                }
            float tr = sxx + syy;
            outv = sxx * syy - sxy * sxy - 0.04f * tr * tr;
        }
        RB[l] = outv;
    }
    __syncthreads();

    // per-wave top-64 over contiguous 448-px chunk
    const int w = tid >> 6, lane = tid & 63;
    const int chunk = w * 448;
    const int gbase = row0 * 224 + chunk;
    uint64_t T = 0;
    #pragma unroll 1
    for (int it = 0; it < 7; it++) {
        float v = RB[chunk + it * 64 + lane];
        uint64_t ck = tk_pack(v, gbase + it * 64 + lane);
        uint64_t thr = __shfl(T, 63, 64);
        if (__ballot(ck > thr)) {
            uint64_t s = tk_sort_asc(ck, lane);
            uint64_t m = (T > s) ? T : s;
            T = tk_clean_desc(m, lane);
        }
    }
    cand[((size_t)b * TKW + r * 4 + w) * 64 + lane] = T;
}

// ---------------------------------------------------------------------------
// K2: merge 112 sorted runs per image.
// ---------------------------------------------------------------------------
__global__ __launch_bounds__(1024) void k_topk_merge(const uint64_t* __restrict__ cand,
                                                     int* __restrict__ kp) {
    const int img = blockIdx.x;
    const int w = threadIdx.x >> 6, lane = threadIdx.x & 63;
    const uint64_t* cb = cand + (size_t)img * TKW * 64;
    __shared__ uint64_t S[16 * 64];

    uint64_t T = cb[(w * 7) * 64 + lane];
    #pragma unroll
    for (int r = 1; r < 7; r++) {
        uint64_t C = cb[(w * 7 + r) * 64 + (63 - lane)];
        uint64_t m = (T > C) ? T : C;
        T = tk_clean_desc(m, lane);
    }
    S[w * 64 + lane] = T;
    __syncthreads();
    if (w == 0) {
        uint64_t T2 = S[lane];
        #pragma unroll
        for (int r = 1; r < 16; r++) {
            uint64_t C = S[r * 64 + (63 - lane)];
            uint64_t m = (T2 > C) ? T2 : C;
            T2 = tk_clean_desc(m, lane);
        }
        kp[img * KP + lane] = (int)(~(uint32_t)T2);
    }
}

// ---------------------------------------------------------------------------
// K3: bilinear patch extraction (faithful swapped broadcast) + conv + relu.
// Padded P[3][18][18] halo; conv from registers; weights via scalar cache.
// ---------------------------------------------------------------------------
__device__ __forceinline__ float gat4(const float* img, float xf, float yf) {
    bool valid = (xf >= 0.f) && (xf < 224.f) && (yf >= 0.f) && (yf < 224.f);
    if (!valid) return 0.f;
    int xi = (int)fminf(fmaxf(xf, 0.f), 223.f);
    int yi = (int)fminf(fmaxf(yf, 0.f), 223.f);
    return img[yi * HW + xi];
}

__global__ __launch_bounds__(256) void k_patch_conv(
    const float* __restrict__ x, const int* __restrict__ kp,
    const float* __restrict__ conv_w, const float* __restrict__ conv_b,
    float* __restrict__ h) {
    const int s = blockIdx.x;   // keypoint slot
    const int b = blockIdx.y;   // image
    const int tid = threadIdx.x;

    __shared__ float P[3][18][18];   // padded halo, border = 0

    const int idx = kp[b * KP + s];
    const int row = idx / HW, col = idx % HW;
    float cy = ((float)row / 224.0f - 0.5f) * 2.0f;
    float cx = ((float)col / 224.0f - 0.5f) * 2.0f;
    cy = fminf(fmaxf(cy, -1.0f), 1.0f);
    cx = fminf(fmaxf(cx, -1.0f), 1.0f);
    const float y01 = (cy + 1.0f) * 0.5f;
    const float x01 = (cx + 1.0f) * 0.5f;
    const float rr = 16.0f / 224.0f;
    const float step = (2.0f * rr) / 15.0f;
    const float* xb = x + (size_t)b * 3 * NPIX;

    for (int e = tid; e < 972; e += 256) {
        int c = e / 324, rem = e - c * 324;
        int yy = rem / 18, xx = rem - yy * 18;
        float val = 0.f;
        if (yy >= 1 && yy <= 16 && xx >= 1 && xx <= 16) {
            int i = yy - 1, j = xx - 1;
            float pj = (j == 15) ? rr : (-rr + (float)j * step);
            float pi = (i == 15) ? rr : (-rr + (float)i * step);
            // faithful bug: x-coordinate uses y01 (row), y-coordinate uses x01 (col)
            float gxn = (pj + y01) * 2.0f - 1.0f;
            float gyn = (pi + x01) * 2.0f - 1.0f;
            float gx = (gxn + 1.0f) * 0.5f * 223.0f;
            float gy = (gyn + 1.0f) * 0.5f * 223.0f;
            float x0 = floorf(gx), y0 = floorf(gy);
            float x1 = x0 + 1.0f, y1 = y0 + 1.0f;
            float wx1 = gx - x0, wy1 = gy - y0;
            float wx0 = 1.0f - wx1, wy0 = 1.0f - wy1;
            const float* img = xb + (size_t)c * NPIX;
            val = gat4(img, x0, y0) * (wx0 * wy0)
                + gat4(img, x1, y0) * (wx1 * wy0)
                + gat4(img, x0, y1) * (wx0 * wy1)
                + gat4(img, x1, y1) * (wx1 * wy1);
        }
        P[c][yy][xx] = val;
    }
    __syncthreads();

    const int i = tid >> 4, j = tid & 15;
    float acc[8];
    #pragma unroll
    for (int co = 0; co < 8; co++) acc[co] = conv_b[co];   // uniform -> s_load
    #pragma unroll
    for (int ci = 0; ci < 3; ci++) {
        float n[9];
        #pragma unroll
        for (int di = 0; di < 3; di++)
            #pragma unroll
            for (int dj = 0; dj < 3; dj++)
                n[di * 3 + dj] = P[ci][i + di][j + dj];
        #pragma unroll
        for (int co = 0; co < 8; co++) {
            float a = acc[co];
            #pragma unroll
            for (int u = 0; u < 9; u++)
                a += n[u] * conv_w[co * 27 + ci * 9 + u];  // uniform -> s_load
            acc[co] = a;
        }
    }
    const size_t mbase = ((size_t)(b * KP + s)) * 2048;
    #pragma unroll
    for (int co = 0; co < 8; co++)
        h[mbase + co * 256 + tid] = fmaxf(acc[co], 0.0f);
}

// ---------------------------------------------------------------------------
// K4: fc1 partial GEMM, 4x8 register tile (was 4x4).
// grid (32 m-tiles of 64, 16 k-slices) x 128 threads (2 waves).
// Per k: 1 a-b128 + 2 w-b128 -> 32 FMA (FMA:b128 = 10.7 vs old 8).
// LDS 2x 64x69 floats = 35 KB -> 4 blocks/CU, 8 waves/CU.
// ---------------------------------------------------------------------------
__global__ __launch_bounds__(128) void k_fc1(
    const float* __restrict__ h, const float* __restrict__ fc1_w,
    float* __restrict__ partial) {
    const int mt = blockIdx.x;          // 0..31
    const int ks = blockIdx.y;          // 0..15
    const int tid = threadIdx.x;        // 0..127
    const int M0 = mt * 64;
    const int og = tid >> 4, mg = tid & 15;   // og 0..7 (o-block og*8), mg 0..15 (m-block mg*4)
    __shared__ float A[64 * FC1_LS];    // [k][m], pad 69 (stride*4 mod 32 banks ~2-way)
    __shared__ float W[64 * FC1_LS];    // [k][o]
    float acc[4][8];
    #pragma unroll
    for (int i = 0; i < 4; i++)
        #pragma unroll
        for (int j = 0; j < 8; j++) acc[i][j] = 0.f;

    const int rr0 = tid >> 2;           // 0..31
    const int kc = (tid & 3) * 16;      // 0,16,32,48

    #pragma unroll 1
    for (int ch = 0; ch < 2; ch++) {
        const int k0 = ks * 128 + ch * 64;
        __syncthreads();
        #pragma unroll
        for (int p = 0; p < 2; p++) {
            int rw = p * 32 + rr0;      // 0..63 : m-row for A, o-row for W
            const float* hp = &h[(size_t)(M0 + rw) * 2048 + k0 + kc];
            const float* wp = &fc1_w[(size_t)rw * 2048 + k0 + kc];
            #pragma unroll
            for (int q = 0; q < 4; q++) {
                float4 av = *(const float4*)(hp + q * 4);
                float4 wv = *(const float4*)(wp + q * 4);
                int kb = kc + q * 4;
                A[(kb + 0) * FC1_LS + rw] = av.x;
                A[(kb + 1) * FC1_LS + rw] = av.y;
                A[(kb + 2) * FC1_LS + rw] = av.z;
                A[(kb + 3) * FC1_LS + rw] = av.w;
                W[(kb + 0) * FC1_LS + rw] = wv.x;
                W[(kb + 1) * FC1_LS + rw] = wv.y;
                W[(kb + 2) * FC1_LS + rw] = wv.z;
                W[(kb + 3) * FC1_LS + rw] = wv.w;
            }
        }
        __syncthreads();
        #pragma unroll 4
        for (int k = 0; k < 64; k++) {
            float4 a  = *(float4*)&A[k * FC1_LS + mg * 4];
            float4 w0 = *(float4*)&W[k * FC1_LS + og * 8];
            float4 w1 = *(float4*)&W[k * FC1_LS + og * 8 + 4];
            float av[4] = {a.x, a.y, a.z, a.w};
            #pragma unroll
            for (int i = 0; i < 4; i++) {
                acc[i][0] += av[i] * w0.x; acc[i][1] += av[i] * w0.y;
                acc[i][2] += av[i] * w0.z; acc[i][3] += av[i] * w0.w;
                acc[i][4] += av[i] * w1.x; acc[i][5] += av[i] * w1.y;
                acc[i][6] += av[i] * w1.z; acc[i][7] += av[i] * w1.w;
            }
        }
    }
    float* pb = partial + (size_t)ks * 131072;
    #pragma unroll
    for (int i = 0; i < 4; i++) {
        size_t m = (size_t)(M0 + mg * 4 + i);
        *(float4*)&pb[m * 64 + og * 8] =
            make_float4(acc[i][0], acc[i][1], acc[i][2], acc[i][3]);
        *(float4*)&pb[m * 64 + og * 8 + 4] =
            make_float4(acc[i][4], acc[i][5], acc[i][6], acc[i][7]);
    }
}

// Sum 16 partials + bias + relu -> feat[b][4096] (coalesced identity store);
// also seed out[b][c] = fc2_b[c] (fc2 atomically accumulates later).
__global__ __launch_bounds__(256) void k_fc1_post(
    const float* __restrict__ partial, const float* __restrict__ fc1_b,
    const float* __restrict__ fc2_b, float* __restrict__ feat,
    float* __restrict__ out) {
    const int id = blockIdx.x * 256 + threadIdx.x;   // 0..131071
    const int o = id & 63;
    float s = 0.f;
    #pragma unroll
    for (int ks = 0; ks < FC1_KS; ks++) s += partial[(size_t)ks * 131072 + id];
    s = fmaxf(s + fc1_b[o], 0.f);
    feat[id] = s;                                    // [b][k] layout
    if (id < BATCH * NCLS) out[id] = fc2_b[id % NCLS];
}

// ---------------------------------------------------------------------------
// K5: fc2 out[b][c] += sum_k feat[b][k]*fc2_w[c][k], K split 4 ways.
// No-LDS main loop: W streamed global->reg (read exactly once, lanes form
// 128B-coalesced groups with 8-way broadcast), F direct from L2-hot feat.
// Only the final cross-kg reduction touches LDS. grid (125, 4).
// ---------------------------------------------------------------------------
#define RED_S 260
__global__ __launch_bounds__(256) void k_fc2(
    const float* __restrict__ feat, const float* __restrict__ fc2_w,
    float* __restrict__ out) {
    const int c0 = blockIdx.x * 8;
    const int kq = blockIdx.y * 1024;
    const int tid = threadIdx.x;
    const int bq = tid & 7, kg = tid >> 3;          // b-quad, k-group 0..31
    __shared__ float Red[32 * RED_S];               // [kg][cl*32+b], padded

    float4 acc[8];
    #pragma unroll
    for (int cl = 0; cl < 8; cl++) acc[cl] = make_float4(0.f, 0.f, 0.f, 0.f);

    #pragma unroll 2
    for (int ch = 0; ch < 8; ch++) {
        const int k0 = kq + ch * 128;
        const float* fp = feat + (size_t)(bq * 4) * 4096 + k0 + kg * 4;
        float4 f0 = *(const float4*)(fp);
        float4 f1 = *(const float4*)(fp + 4096);
        float4 f2 = *(const float4*)(fp + 8192);
        float4 f3 = *(const float4*)(fp + 12288);
        const float* wp = fc2_w + (size_t)c0 * 4096 + k0 + kg * 4;
        #pragma unroll
        for (int cl = 0; cl < 8; cl++) {
            float4 w = *(const float4*)(wp + (size_t)cl * 4096);
            acc[cl].x += w.x * f0.x + w.y * f0.y + w.z * f0.z + w.w * f0.w;
            acc[cl].y += w.x * f1.x + w.y * f1.y + w.z * f1.z + w.w * f1.w;
            acc[cl].z += w.x * f2.x + w.y * f2.y + w.z * f2.z + w.w * f2.w;
            acc[cl].w += w.x * f3.x + w.y * f3.y + w.z * f3.z + w.w * f3.w;
        }
    }

    #pragma unroll
    for (int cl = 0; cl < 8; cl++)
        *(float4*)&Red[kg * RED_S + cl * 32 + bq * 4] = acc[cl];
    __syncthreads();

    const int cl2 = tid >> 5, b2 = tid & 31;
    float s = 0.f;
    #pragma unroll
    for (int g = 0; g < 32; g++) s += Red[g * RED_S + cl2 * 32 + b2];
    atomicAdd(&out[b2 * NCLS + c0 + cl2], s);
}

// ---------------------------------------------------------------------------
extern "C" void kernel_launch(void* const* d_in, const int* in_sizes, int n_in,
                              void* d_out, int out_size, void* d_ws, size_t ws_size,
                              hipStream_t stream) {
    const float* x      = (const float*)d_in[0];
    const float* conv_w = (const float*)d_in[1];
    const float* conv_b = (const float*)d_in[2];
    const float* fc1_w  = (const float*)d_in[3];
    const float* fc1_b  = (const float*)d_in[4];
    const float* fc2_w  = (const float*)d_in[5];
    const float* fc2_b  = (const float*)d_in[6];
    float* out = (float*)d_out;

    // ws layout. Region0 (8.39 MB): cand (1.84 MB) early, then reused as
    // fc1 partial[16][2048][64] — cand is dead before k_fc1 (stream-ordered).
    char* base = (char*)d_ws;
    const size_t region0 = (size_t)FC1_KS * 2048 * 64 * 4;       // 8.39 MB
    uint64_t* cand    = (uint64_t*)base;                         // 1.84 MB
    float*    partial = (float*)base;                            // alias
    float*    h       = (float*)(base + region0);                // 16.78 MB
    float*    feat    = h + (size_t)2048 * 2048;                 // 0.52 MB  [b][4096]
    int*      kp      = (int*)(feat + (size_t)4096 * 32);        // 8 KB

    k_harris_topk<<<dim3(28, 32), 256, 0, stream>>>(x, cand);
    k_topk_merge<<<32, 1024, 0, stream>>>(cand, kp);
    k_patch_conv<<<dim3(KP, BATCH), 256, 0, stream>>>(x, kp, conv_w, conv_b, h);
    k_fc1<<<dim3(32, FC1_KS), 128, 0, stream>>>(h, fc1_w, partial);
    k_fc1_post<<<512, 256, 0, stream>>>(partial, fc1_b, fc2_b, feat, out);
    k_fc2<<<dim3(125, 4), 256, 0, stream>>>(feat, fc2_w, out);
}

// Round 3
// 169.913 us; speedup vs baseline: 1.0648x; 1.0648x over previous
//
#include <hip/hip_runtime.h>
#include <cstdint>
#include <math.h>

#define HW 224
#define NPIX (HW*HW)          // 50176 = 784*64
#define BATCH 32
#define KP 64
#define PS 16
#define NCLS 1000
#define TKW 112               // 64-candidate runs per image (28 bands x 4 waves)
#define FC1_KS 16             // fc1 K-split

// ---------------------------------------------------------------------------
// Top-64 helpers: in-wave bitonic selection on packed 64-bit keys.
// key = monotone(value) << 32 | ~index  -> order == (value desc, index asc).
// ---------------------------------------------------------------------------
__device__ __forceinline__ uint64_t tk_pack(float v, int idx) {
    uint32_t u = __float_as_uint(v);
    u = (u & 0x80000000u) ? ~u : (u | 0x80000000u);
    return ((uint64_t)u << 32) | (uint32_t)(~idx);
}

__device__ __forceinline__ uint64_t tk_sort_asc(uint64_t k, int lane) {
    #pragma unroll
    for (int size = 2; size <= 64; size <<= 1) {
        #pragma unroll
        for (int stride = size >> 1; stride >= 1; stride >>= 1) {
            uint64_t o = __shfl_xor(k, stride, 64);
            bool up = ((lane & size) == 0);
            bool keepmax = (((lane & stride) != 0) == up);
            k = keepmax ? (k > o ? k : o) : (k < o ? k : o);
        }
    }
    return k;
}

__device__ __forceinline__ uint64_t tk_clean_desc(uint64_t k, int lane) {
    #pragma unroll
    for (int stride = 32; stride >= 1; stride >>= 1) {
        uint64_t o = __shfl_xor(k, stride, 64);
        bool keepmax = ((lane & stride) == 0);
        k = keepmax ? (k > o ? k : o) : (k < o ? k : o);
    }
    return k;
}

// ---------------------------------------------------------------------------
// K1: FUSED Harris + per-band top-64. One block per (8-row band, image).
// R3: Sobel and Harris restructured to 7-contiguous-column runs per thread.
// Windows are loaded into registers once (3x9 per operand), cutting LDS
// scalar reads ~7x while keeping the accumulation order bit-identical.
// ---------------------------------------------------------------------------
__global__ __launch_bounds__(256) void k_harris_topk(const float* __restrict__ x,
                                                     uint64_t* __restrict__ cand) {
    const int r = blockIdx.x, b = blockIdx.y;
    const int tid = threadIdx.x;
    const int row0 = r * 8;
    __shared__ float G[12][228];
    __shared__ float DXs[10][228];
    __shared__ float DYs[10][228];
    __shared__ float RB[1792];
    const float* xb = x + (size_t)b * 3 * NPIX;

    // grayscale stage (stored at col+1; cols 0 and 225 are zero pads)
    for (int l = tid; l < 12 * 224; l += 256) {
        int gr = l / 224, gc = l % 224;
        int gy = row0 - 2 + gr;
        float v = 0.f;
        if (gy >= 0 && gy < HW) {
            int o = gy * HW + gc;
            v = (xb[o] + xb[NPIX + o] + xb[2 * NPIX + o]) / 3.0f;
        }
        G[gr][gc + 1] = v;
    }
    if (tid < 12) { G[tid][0] = 0.f; G[tid][225] = 0.f; }
    if (tid < 10) { DXs[tid][0] = 0.f; DXs[tid][225] = 0.f;
                    DYs[tid][0] = 0.f; DYs[tid][225] = 0.f; }
    __syncthreads();

    // Sobel dx/dy: 320 runs (10 rows x 32 runs of 7 cols). Per run: 27 LDS
    // reads into registers -> 7 outputs (was ~12 reads per output).
    for (int rid = tid; rid < 320; rid += 256) {
        int dr = rid >> 5, cb = (rid & 31) * 7;
        int ay = row0 - 1 + dr;
        float g0[9], g1[9], g2[9];
        #pragma unroll
        for (int v = 0; v < 9; v++) {
            g0[v] = G[dr][cb + v];
            g1[v] = G[dr + 1][cb + v];
            g2[v] = G[dr + 2][cb + v];
        }
        bool ok = (ay >= 0 && ay < HW);
        #pragma unroll
        for (int t = 0; t < 7; t++) {
            float dxv = 0.f, dyv = 0.f;
            if (ok) {
                dxv = (g0[t + 2] - g0[t]) + (g1[t + 2] - g1[t]) +
                      (g2[t + 2] - g2[t]);
                dyv = (g2[t] + g2[t + 1] + g2[t + 2]) -
                      (g0[t] + g0[t + 1] + g0[t + 2]);
            }
            DXs[dr][cb + t + 1] = dxv;
            DYs[dr][cb + t + 1] = dyv;
        }
    }
    __syncthreads();

    // Harris: exactly 256 runs (8 rows x 32 runs of 7). 54 LDS reads/thread
    // (was 378); accumulation order identical to reference kernel.
    {
        const int rr = tid >> 5, cb = (tid & 31) * 7;
        const int gy = row0 + rr;
        float dxw[3][9], dyw[3][9];
        #pragma unroll
        for (int u = 0; u < 3; u++)
            #pragma unroll
            for (int v = 0; v < 9; v++) {
                dxw[u][v] = DXs[rr + u][cb + v];
                dyw[u][v] = DYs[rr + u][cb + v];
            }
        const bool rowok = (gy >= PS && gy < HW - PS);
        const float gw[3][3] = {{1.f/16.f, 2.f/16.f, 1.f/16.f},
                                {2.f/16.f, 4.f/16.f, 2.f/16.f},
                                {1.f/16.f, 2.f/16.f, 1.f/16.f}};
        #pragma unroll
        for (int t = 0; t < 7; t++) {
            int c = cb + t;
            float outv = 0.f;
            if (rowok && c >= PS && c < HW - PS) {
                float sxx = 0.f, syy = 0.f, sxy = 0.f;
                #pragma unroll
                for (int u = 0; u < 3; u++)
                    #pragma unroll
                    for (int v = 0; v < 3; v++) {
                        float dv = dxw[u][t + v];
                        float ev = dyw[u][t + v];
                        float w = gw[u][v];
                        sxx += w * dv * dv;
                        syy += w * ev * ev;
                        sxy += w * dv * ev;
                    }
                float tr = sxx + syy;
                outv = sxx * syy - sxy * sxy - 0.04f * tr * tr;
            }
            RB[rr * 224 + c] = outv;
        }
    }
    __syncthreads();

    // per-wave top-64 over contiguous 448-px chunk
    const int w = tid >> 6, lane = tid & 63;
    const int chunk = w * 448;
    const int gbase = row0 * 224 + chunk;
    uint64_t T = 0;
    #pragma unroll 1
    for (int it = 0; it < 7; it++) {
        float v = RB[chunk + it * 64 + lane];
        uint64_t ck = tk_pack(v, gbase + it * 64 + lane);
        uint64_t thr = __shfl(T, 63, 64);
        if (__ballot(ck > thr)) {
            uint64_t s = tk_sort_asc(ck, lane);
            uint64_t m = (T > s) ? T : s;
            T = tk_clean_desc(m, lane);
        }
    }
    cand[((size_t)b * TKW + r * 4 + w) * 64 + lane] = T;
}

// ---------------------------------------------------------------------------
// K2: merge 112 sorted runs per image.
// ---------------------------------------------------------------------------
__global__ __launch_bounds__(1024) void k_topk_merge(const uint64_t* __restrict__ cand,
                                                     int* __restrict__ kp) {
    const int img = blockIdx.x;
    const int w = threadIdx.x >> 6, lane = threadIdx.x & 63;
    const uint64_t* cb = cand + (size_t)img * TKW * 64;
    __shared__ uint64_t S[16 * 64];

    uint64_t T = cb[(w * 7) * 64 + lane];
    #pragma unroll
    for (int r = 1; r < 7; r++) {
        uint64_t C = cb[(w * 7 + r) * 64 + (63 - lane)];
        uint64_t m = (T > C) ? T : C;
        T = tk_clean_desc(m, lane);
    }
    S[w * 64 + lane] = T;
    __syncthreads();
    if (w == 0) {
        uint64_t T2 = S[lane];
        #pragma unroll
        for (int r = 1; r < 16; r++) {
            uint64_t C = S[r * 64 + (63 - lane)];
            uint64_t m = (T2 > C) ? T2 : C;
            T2 = tk_clean_desc(m, lane);
        }
        kp[img * KP + lane] = (int)(~(uint32_t)T2);
    }
}

// ---------------------------------------------------------------------------
// K3: bilinear patch extraction (faithful swapped broadcast) + conv + relu.
// Padded P[3][18][18] halo; conv from registers; weights via scalar cache.
// ---------------------------------------------------------------------------
__device__ __forceinline__ float gat4(const float* img, float xf, float yf) {
    bool valid = (xf >= 0.f) && (xf < 224.f) && (yf >= 0.f) && (yf < 224.f);
    if (!valid) return 0.f;
    int xi = (int)fminf(fmaxf(xf, 0.f), 223.f);
    int yi = (int)fminf(fmaxf(yf, 0.f), 223.f);
    return img[yi * HW + xi];
}

__global__ __launch_bounds__(256) void k_patch_conv(
    const float* __restrict__ x, const int* __restrict__ kp,
    const float* __restrict__ conv_w, const float* __restrict__ conv_b,
    float* __restrict__ h) {
    const int s = blockIdx.x;   // keypoint slot
    const int b = blockIdx.y;   // image
    const int tid = threadIdx.x;

    __shared__ float P[3][18][18];   // padded halo, border = 0

    const int idx = kp[b * KP + s];
    const int row = idx / HW, col = idx % HW;
    float cy = ((float)row / 224.0f - 0.5f) * 2.0f;
    float cx = ((float)col / 224.0f - 0.5f) * 2.0f;
    cy = fminf(fmaxf(cy, -1.0f), 1.0f);
    cx = fminf(fmaxf(cx, -1.0f), 1.0f);
    const float y01 = (cy + 1.0f) * 0.5f;
    const float x01 = (cx + 1.0f) * 0.5f;
    const float rr = 16.0f / 224.0f;
    const float step = (2.0f * rr) / 15.0f;
    const float* xb = x + (size_t)b * 3 * NPIX;

    for (int e = tid; e < 972; e += 256) {
        int c = e / 324, rem = e - c * 324;
        int yy = rem / 18, xx = rem - yy * 18;
        float val = 0.f;
        if (yy >= 1 && yy <= 16 && xx >= 1 && xx <= 16) {
            int i = yy - 1, j = xx - 1;
            float pj = (j == 15) ? rr : (-rr + (float)j * step);
            float pi = (i == 15) ? rr : (-rr + (float)i * step);
            // faithful bug: x-coordinate uses y01 (row), y-coordinate uses x01 (col)
            float gxn = (pj + y01) * 2.0f - 1.0f;
            float gyn = (pi + x01) * 2.0f - 1.0f;
            float gx = (gxn + 1.0f) * 0.5f * 223.0f;
            float gy = (gyn + 1.0f) * 0.5f * 223.0f;
            float x0 = floorf(gx), y0 = floorf(gy);
            float x1 = x0 + 1.0f, y1 = y0 + 1.0f;
            float wx1 = gx - x0, wy1 = gy - y0;
            float wx0 = 1.0f - wx1, wy0 = 1.0f - wy1;
            const float* img = xb + (size_t)c * NPIX;
            val = gat4(img, x0, y0) * (wx0 * wy0)
                + gat4(img, x1, y0) * (wx1 * wy0)
                + gat4(img, x0, y1) * (wx0 * wy1)
                + gat4(img, x1, y1) * (wx1 * wy1);
        }
        P[c][yy][xx] = val;
    }
    __syncthreads();

    const int i = tid >> 4, j = tid & 15;
    float acc[8];
    #pragma unroll
    for (int co = 0; co < 8; co++) acc[co] = conv_b[co];   // uniform -> s_load
    #pragma unroll
    for (int ci = 0; ci < 3; ci++) {
        float n[9];
        #pragma unroll
        for (int di = 0; di < 3; di++)
            #pragma unroll
            for (int dj = 0; dj < 3; dj++)
                n[di * 3 + dj] = P[ci][i + di][j + dj];
        #pragma unroll
        for (int co = 0; co < 8; co++) {
            float a = acc[co];
            #pragma unroll
            for (int u = 0; u < 9; u++)
                a += n[u] * conv_w[co * 27 + ci * 9 + u];  // uniform -> s_load
            acc[co] = a;
        }
    }
    const size_t mbase = ((size_t)(b * KP + s)) * 2048;
    #pragma unroll
    for (int co = 0; co < 8; co++)
        h[mbase + co * 256 + tid] = fmaxf(acc[co], 0.0f);
}

// ---------------------------------------------------------------------------
// K4: fc1 partial GEMM. grid (32 m-tiles, 16 k-slices) x 256.  (R1 version)
// ---------------------------------------------------------------------------
__global__ __launch_bounds__(256) void k_fc1(
    const float* __restrict__ h, const float* __restrict__ fc1_w,
    float* __restrict__ partial) {
    const int mt = blockIdx.x;          // 0..31
    const int ks = blockIdx.y;          // 0..15
    const int tid = threadIdx.x;
    const int M0 = mt * 64;
    const int og = tid >> 4, mg = tid & 15;
    __shared__ float A[64 * 68];        // [k][m]
    __shared__ float W[64 * 68];        // [k][o]
    float acc[4][4];
    #pragma unroll
    for (int i = 0; i < 4; i++)
        #pragma unroll
        for (int j = 0; j < 4; j++) acc[i][j] = 0.f;

    #pragma unroll 1
    for (int ch = 0; ch < 2; ch++) {
        const int k0 = ks * 128 + ch * 64;
        __syncthreads();
        #pragma unroll
        for (int p = 0; p < 4; p++) {
            int row = p * 16 + (tid >> 4);      // 0..63
            int c0 = (tid & 15) * 4;            // k offset 0..60
            float4 av = *(const float4*)&h[(size_t)(M0 + row) * 2048 + k0 + c0];
            A[(c0 + 0) * 68 + row] = av.x;
            A[(c0 + 1) * 68 + row] = av.y;
            A[(c0 + 2) * 68 + row] = av.z;
            A[(c0 + 3) * 68 + row] = av.w;
            float4 wv = *(const float4*)&fc1_w[(size_t)row * 2048 + k0 + c0];
            W[(c0 + 0) * 68 + row] = wv.x;
            W[(c0 + 1) * 68 + row] = wv.y;
            W[(c0 + 2) * 68 + row] = wv.z;
            W[(c0 + 3) * 68 + row] = wv.w;
        }
        __syncthreads();
        #pragma unroll 4
        for (int k = 0; k < 64; k++) {
            float4 a = *(float4*)&A[k * 68 + mg * 4];
            float4 w = *(float4*)&W[k * 68 + og * 4];
            acc[0][0] += a.x * w.x; acc[0][1] += a.x * w.y;
            acc[0][2] += a.x * w.z; acc[0][3] += a.x * w.w;
            acc[1][0] += a.y * w.x; acc[1][1] += a.y * w.y;
            acc[1][2] += a.y * w.z; acc[1][3] += a.y * w.w;
            acc[2][0] += a.z * w.x; acc[2][1] += a.z * w.y;
            acc[2][2] += a.z * w.z; acc[2][3] += a.z * w.w;
            acc[3][0] += a.w * w.x; acc[3][1] += a.w * w.y;
            acc[3][2] += a.w * w.z; acc[3][3] += a.w * w.w;
        }
    }
    float* pb = partial + ((size_t)ks * 2048 + M0) * 64;
    #pragma unroll
    for (int mi = 0; mi < 4; mi++) {
        float4 v = make_float4(acc[mi][0], acc[mi][1], acc[mi][2], acc[mi][3]);
        *(float4*)&pb[(mg * 4 + mi) * 64 + og * 4] = v;
    }
}

// Sum 16 partials + bias + relu -> feat[b][4096] (coalesced identity store);
// also seed out[b][c] = fc2_b[c] (fc2 atomically accumulates later).
__global__ __launch_bounds__(256) void k_fc1_post(
    const float* __restrict__ partial, const float* __restrict__ fc1_b,
    const float* __restrict__ fc2_b, float* __restrict__ feat,
    float* __restrict__ out) {
    const int id = blockIdx.x * 256 + threadIdx.x;   // 0..131071
    const int o = id & 63;
    float s = 0.f;
    #pragma unroll
    for (int ks = 0; ks < FC1_KS; ks++) s += partial[(size_t)ks * 131072 + id];
    s = fmaxf(s + fc1_b[o], 0.f);
    feat[id] = s;                                    // [b][k] layout
    if (id < BATCH * NCLS) out[id] = fc2_b[id % NCLS];
}

// ---------------------------------------------------------------------------
// K5: fc2 out[b][c] += sum_k feat[b][k]*fc2_w[c][k], K split 16 ways.
// (R1 version — LDS-staged F2/Wc, grid (125,16).)
// ---------------------------------------------------------------------------
__global__ __launch_bounds__(256) void k_fc2(
    const float* __restrict__ feat, const float* __restrict__ fc2_w,
    float* __restrict__ out) {
    const int c0 = blockIdx.x * 8;
    const int kbase = blockIdx.y * 256;
    const int tid = threadIdx.x;
    const int bq = tid & 7, kg = tid >> 3;          // b4 = bq*4; kg 0..31

    __shared__ float U[8192];                       // 32 KB union
    float* F2 = U;                                  // [32][132]
    float* Wc = U + 32 * 132;                       // [8][128]
    float* Red = U;                                 // [32][8][32] (aliased)

    float4 acc[8];
    #pragma unroll
    for (int cl = 0; cl < 8; cl++) acc[cl] = make_float4(0.f, 0.f, 0.f, 0.f);

    #pragma unroll 1
    for (int ch = 0; ch < 2; ch++) {
        const int k0 = kbase + ch * 128;
        __syncthreads();
        #pragma unroll
        for (int it = 0; it < 4; it++) {
            int l = it * 256 + tid;
            int bb = l >> 5, kc = (l & 31) << 2;
            *(float4*)&F2[bb * 132 + kc] =
                *(const float4*)&feat[(size_t)bb * 4096 + k0 + kc];
        }
        {
            int cl = tid >> 5, kc = (tid & 31) << 2;
            *(float4*)&Wc[cl * 128 + kc] =
                *(const float4*)&fc2_w[(size_t)(c0 + cl) * 4096 + k0 + kc];
        }
        __syncthreads();
        float4 f0 = *(float4*)&F2[(bq * 4 + 0) * 132 + kg * 4];
        float4 f1 = *(float4*)&F2[(bq * 4 + 1) * 132 + kg * 4];
        float4 f2 = *(float4*)&F2[(bq * 4 + 2) * 132 + kg * 4];
        float4 f3 = *(float4*)&F2[(bq * 4 + 3) * 132 + kg * 4];
        #pragma unroll
        for (int cl = 0; cl < 8; cl++) {
            float4 w = *(float4*)&Wc[cl * 128 + kg * 4];
            acc[cl].x += w.x * f0.x + w.y * f0.y + w.z * f0.z + w.w * f0.w;
            acc[cl].y += w.x * f1.x + w.y * f1.y + w.z * f1.z + w.w * f1.w;
            acc[cl].z += w.x * f2.x + w.y * f2.y + w.z * f2.z + w.w * f2.w;
            acc[cl].w += w.x * f3.x + w.y * f3.y + w.z * f3.z + w.w * f3.w;
        }
    }

    __syncthreads();   // all F2/Wc reads done before Red aliases the memory
    #pragma unroll
    for (int cl = 0; cl < 8; cl++)
        *(float4*)&Red[kg * 256 + cl * 32 + bq * 4] = acc[cl];
    __syncthreads();

    const int cl2 = tid >> 5, b2 = tid & 31;
    float s = 0.f;
    #pragma unroll
    for (int g = 0; g < 32; g++) s += Red[g * 256 + cl2 * 32 + b2];
    atomicAdd(&out[b2 * NCLS + c0 + cl2], s);
}

// ---------------------------------------------------------------------------
extern "C" void kernel_launch(void* const* d_in, const int* in_sizes, int n_in,
                              void* d_out, int out_size, void* d_ws, size_t ws_size,
                              hipStream_t stream) {
    const float* x      = (const float*)d_in[0];
    const float* conv_w = (const float*)d_in[1];
    const float* conv_b = (const float*)d_in[2];
    const float* fc1_w  = (const float*)d_in[3];
    const float* fc1_b  = (const float*)d_in[4];
    const float* fc2_w  = (const float*)d_in[5];
    const float* fc2_b  = (const float*)d_in[6];
    float* out = (float*)d_out;

    // ws layout. Region0 (8.39 MB): cand (1.84 MB) early, then reused as
    // fc1 partial[16][2048][64] — cand is dead before k_fc1 (stream-ordered).
    char* base = (char*)d_ws;
    const size_t region0 = (size_t)FC1_KS * 2048 * 64 * 4;       // 8.39 MB
    uint64_t* cand    = (uint64_t*)base;                         // 1.84 MB
    float*    partial = (float*)base;                            // alias
    float*    h       = (float*)(base + region0);                // 16.78 MB
    float*    feat    = h + (size_t)2048 * 2048;                 // 0.52 MB  [b][4096]
    int*      kp      = (int*)(feat + (size_t)4096 * 32);        // 8 KB

    k_harris_topk<<<dim3(28, 32), 256, 0, stream>>>(x, cand);
    k_topk_merge<<<32, 1024, 0, stream>>>(cand, kp);
    k_patch_conv<<<dim3(KP, BATCH), 256, 0, stream>>>(x, kp, conv_w, conv_b, h);
    k_fc1<<<dim3(32, FC1_KS), 256, 0, stream>>>(h, fc1_w, partial);
    k_fc1_post<<<512, 256, 0, stream>>>(partial, fc1_b, fc2_b, feat, out);
    k_fc2<<<dim3(125, 16), 256, 0, stream>>>(feat, fc2_w, out);
}

// Round 4
// 160.663 us; speedup vs baseline: 1.1261x; 1.0576x over previous
//
#include <hip/hip_runtime.h>
#include <cstdint>
#include <math.h>

#define HW 224
#define NPIX (HW*HW)          // 50176 = 784*64
#define BATCH 32
#define KP 64
#define PS 16
#define NCLS 1000
#define TKB 28                // candidate runs per image (one per band-block)
#define FC1_KS 16             // fc1 K-split

// ---------------------------------------------------------------------------
// Top-64 helpers: in-wave bitonic selection on packed 64-bit keys.
// key = monotone(value) << 32 | ~index  -> order == (value desc, index asc).
// Shuffles hand-lowered by stride: 1,2 -> DPP quad_perm (VALU pipe);
// 4,8,16 -> ds_swizzle (1 LDS op per word); 32 -> generic shfl.
// Bit-exact vs __shfl_xor version (same permutation network).
// ---------------------------------------------------------------------------
__device__ __forceinline__ uint64_t tk_pack(float v, int idx) {
    uint32_t u = __float_as_uint(v);
    u = (u & 0x80000000u) ? ~u : (u | 0x80000000u);
    return ((uint64_t)u << 32) | (uint32_t)(~idx);
}

template<int S>
__device__ __forceinline__ uint64_t sx64(uint64_t k) {
    uint32_t lo = (uint32_t)k, hi = (uint32_t)(k >> 32);
    if constexpr (S == 1) {            // quad_perm [1,0,3,2]
        lo = (uint32_t)__builtin_amdgcn_mov_dpp((int)lo, 0xB1, 0xF, 0xF, true);
        hi = (uint32_t)__builtin_amdgcn_mov_dpp((int)hi, 0xB1, 0xF, 0xF, true);
    } else if constexpr (S == 2) {     // quad_perm [2,3,0,1]
        lo = (uint32_t)__builtin_amdgcn_mov_dpp((int)lo, 0x4E, 0xF, 0xF, true);
        hi = (uint32_t)__builtin_amdgcn_mov_dpp((int)hi, 0x4E, 0xF, 0xF, true);
    } else if constexpr (S <= 16) {    // ds_swizzle bit-mode: xor within 32 lanes
        constexpr int imm = (S << 10) | 0x1F;
        lo = (uint32_t)__builtin_amdgcn_ds_swizzle((int)lo, imm);
        hi = (uint32_t)__builtin_amdgcn_ds_swizzle((int)hi, imm);
    } else {                            // stride 32: cross-half
        lo = (uint32_t)__shfl_xor((int)lo, 32, 64);
        hi = (uint32_t)__shfl_xor((int)hi, 32, 64);
    }
    return ((uint64_t)hi << 32) | lo;
}

#define BSTAGE(SIZE, S) { uint64_t o = sx64<S>(k); \
    bool keepmax = (((lane & S) != 0) == ((lane & SIZE) == 0)); \
    k = keepmax ? (k > o ? k : o) : (k < o ? k : o); }

__device__ __forceinline__ uint64_t tk_sort_asc(uint64_t k, int lane) {
    BSTAGE(2,1)
    BSTAGE(4,2)  BSTAGE(4,1)
    BSTAGE(8,4)  BSTAGE(8,2)  BSTAGE(8,1)
    BSTAGE(16,8) BSTAGE(16,4) BSTAGE(16,2) BSTAGE(16,1)
    BSTAGE(32,16) BSTAGE(32,8) BSTAGE(32,4) BSTAGE(32,2) BSTAGE(32,1)
    BSTAGE(64,32) BSTAGE(64,16) BSTAGE(64,8) BSTAGE(64,4) BSTAGE(64,2) BSTAGE(64,1)
    return k;
}

#define CSTAGE(S) { uint64_t o = sx64<S>(k); \
    bool keepmax = ((lane & S) == 0); \
    k = keepmax ? (k > o ? k : o) : (k < o ? k : o); }

__device__ __forceinline__ uint64_t tk_clean_desc(uint64_t k, int lane) {
    CSTAGE(32) CSTAGE(16) CSTAGE(8) CSTAGE(4) CSTAGE(2) CSTAGE(1)
    return k;
}

// ---------------------------------------------------------------------------
// K1: FUSED Harris + per-band top-64 + in-block merge of the 4 wave runs.
// One block per (8-row band, image); writes ONE sorted 64-run per block.
// ---------------------------------------------------------------------------
__global__ __launch_bounds__(256) void k_harris_topk(const float* __restrict__ x,
                                                     uint64_t* __restrict__ cand) {
    const int r = blockIdx.x, b = blockIdx.y;
    const int tid = threadIdx.x;
    const int row0 = r * 8;
    __shared__ float G[12][228];
    __shared__ float DXs[10][228];
    __shared__ float DYs[10][228];
    __shared__ float RB[1792];
    __shared__ uint64_t SM[4][64];
    const float* xb = x + (size_t)b * 3 * NPIX;

    // grayscale stage (stored at col+1; cols 0 and 225 are zero pads)
    for (int l = tid; l < 12 * 224; l += 256) {
        int gr = l / 224, gc = l % 224;
        int gy = row0 - 2 + gr;
        float v = 0.f;
        if (gy >= 0 && gy < HW) {
            int o = gy * HW + gc;
            v = (xb[o] + xb[NPIX + o] + xb[2 * NPIX + o]) / 3.0f;
        }
        G[gr][gc + 1] = v;
    }
    if (tid < 12) { G[tid][0] = 0.f; G[tid][225] = 0.f; }
    if (tid < 10) { DXs[tid][0] = 0.f; DXs[tid][225] = 0.f;
                    DYs[tid][0] = 0.f; DYs[tid][225] = 0.f; }
    __syncthreads();

    // Sobel dx/dy: 320 runs (10 rows x 32 runs of 7 cols), register windows.
    for (int rid = tid; rid < 320; rid += 256) {
        int dr = rid >> 5, cb = (rid & 31) * 7;
        int ay = row0 - 1 + dr;
        float g0[9], g1[9], g2[9];
        #pragma unroll
        for (int v = 0; v < 9; v++) {
            g0[v] = G[dr][cb + v];
            g1[v] = G[dr + 1][cb + v];
            g2[v] = G[dr + 2][cb + v];
        }
        bool ok = (ay >= 0 && ay < HW);
        #pragma unroll
        for (int t = 0; t < 7; t++) {
            float dxv = 0.f, dyv = 0.f;
            if (ok) {
                dxv = (g0[t + 2] - g0[t]) + (g1[t + 2] - g1[t]) +
                      (g2[t + 2] - g2[t]);
                dyv = (g2[t] + g2[t + 1] + g2[t + 2]) -
                      (g0[t] + g0[t + 1] + g0[t + 2]);
            }
            DXs[dr][cb + t + 1] = dxv;
            DYs[dr][cb + t + 1] = dyv;
        }
    }
    __syncthreads();

    // Harris: 256 runs (8 rows x 32 runs of 7), register windows,
    // accumulation order identical to reference kernel.
    {
        const int rr = tid >> 5, cb = (tid & 31) * 7;
        const int gy = row0 + rr;
        float dxw[3][9], dyw[3][9];
        #pragma unroll
        for (int u = 0; u < 3; u++)
            #pragma unroll
            for (int v = 0; v < 9; v++) {
                dxw[u][v] = DXs[rr + u][cb + v];
                dyw[u][v] = DYs[rr + u][cb + v];
            }
        const bool rowok = (gy >= PS && gy < HW - PS);
        const float gw[3][3] = {{1.f/16.f, 2.f/16.f, 1.f/16.f},
                                {2.f/16.f, 4.f/16.f, 2.f/16.f},
                                {1.f/16.f, 2.f/16.f, 1.f/16.f}};
        #pragma unroll
        for (int t = 0; t < 7; t++) {
            int c = cb + t;
            float outv = 0.f;
            if (rowok && c >= PS && c < HW - PS) {
                float sxx = 0.f, syy = 0.f, sxy = 0.f;
                #pragma unroll
                for (int u = 0; u < 3; u++)
                    #pragma unroll
                    for (int v = 0; v < 3; v++) {
                        float dv = dxw[u][t + v];
                        float ev = dyw[u][t + v];
                        float w = gw[u][v];
                        sxx += w * dv * dv;
                        syy += w * ev * ev;
                        sxy += w * dv * ev;
                    }
                float tr = sxx + syy;
                outv = sxx * syy - sxy * sxy - 0.04f * tr * tr;
            }
            RB[rr * 224 + c] = outv;
        }
    }
    __syncthreads();

    // per-wave top-64 over contiguous 448-px chunk
    const int w = tid >> 6, lane = tid & 63;
    const int chunk = w * 448;
    const int gbase = row0 * 224 + chunk;
    uint64_t T = 0;
    #pragma unroll 1
    for (int it = 0; it < 7; it++) {
        float v = RB[chunk + it * 64 + lane];
        uint64_t ck = tk_pack(v, gbase + it * 64 + lane);
        uint64_t thr = __shfl(T, 63, 64);
        if (__ballot(ck > thr)) {
            uint64_t s = tk_sort_asc(ck, lane);
            uint64_t m = (T > s) ? T : s;
            T = tk_clean_desc(m, lane);
        }
    }

    // in-block merge of the 4 wave runs -> one sorted run per block
    SM[w][lane] = T;
    __syncthreads();
    if (w == 0 || w == 2) {
        uint64_t C = SM[w + 1][63 - lane];
        uint64_t m = (T > C) ? T : C;
        T = tk_clean_desc(m, lane);
        SM[w][lane] = T;
    }
    __syncthreads();
    if (w == 0) {
        uint64_t C = SM[2][63 - lane];
        uint64_t m = (T > C) ? T : C;
        T = tk_clean_desc(m, lane);
        cand[((size_t)b * TKB + r) * 64 + lane] = T;
    }
}

// ---------------------------------------------------------------------------
// K2: merge 28 sorted runs per image. 4 waves x 6 serial merges, then
// wave 0 merges the 4 partials (chain: 9 merges, was 21).
// ---------------------------------------------------------------------------
__global__ __launch_bounds__(256) void k_topk_merge(const uint64_t* __restrict__ cand,
                                                    int* __restrict__ kp) {
    const int img = blockIdx.x;
    const int w = threadIdx.x >> 6, lane = threadIdx.x & 63;
    const uint64_t* cb = cand + (size_t)img * TKB * 64;
    __shared__ uint64_t S[4][64];

    uint64_t T = cb[(w * 7) * 64 + lane];
    #pragma unroll
    for (int r = 1; r < 7; r++) {
        uint64_t C = cb[(w * 7 + r) * 64 + (63 - lane)];
        uint64_t m = (T > C) ? T : C;
        T = tk_clean_desc(m, lane);
    }
    S[w][lane] = T;
    __syncthreads();
    if (w == 0) {
        #pragma unroll
        for (int r = 1; r < 4; r++) {
            uint64_t C = S[r][63 - lane];
            uint64_t m = (T > C) ? T : C;
            T = tk_clean_desc(m, lane);
        }
        kp[img * KP + lane] = (int)(~(uint32_t)T);
    }
}

// ---------------------------------------------------------------------------
// K3: bilinear patch extraction (faithful swapped broadcast) + conv + relu.
// Padded P[3][18][18] halo; conv from registers; weights via scalar cache.
// ---------------------------------------------------------------------------
__device__ __forceinline__ float gat4(const float* img, float xf, float yf) {
    bool valid = (xf >= 0.f) && (xf < 224.f) && (yf >= 0.f) && (yf < 224.f);
    if (!valid) return 0.f;
    int xi = (int)fminf(fmaxf(xf, 0.f), 223.f);
    int yi = (int)fminf(fmaxf(yf, 0.f), 223.f);
    return img[yi * HW + xi];
}

__global__ __launch_bounds__(256) void k_patch_conv(
    const float* __restrict__ x, const int* __restrict__ kp,
    const float* __restrict__ conv_w, const float* __restrict__ conv_b,
    float* __restrict__ h) {
    const int s = blockIdx.x;   // keypoint slot
    const int b = blockIdx.y;   // image
    const int tid = threadIdx.x;

    __shared__ float P[3][18][18];   // padded halo, border = 0

    const int idx = kp[b * KP + s];
    const int row = idx / HW, col = idx % HW;
    float cy = ((float)row / 224.0f - 0.5f) * 2.0f;
    float cx = ((float)col / 224.0f - 0.5f) * 2.0f;
    cy = fminf(fmaxf(cy, -1.0f), 1.0f);
    cx = fminf(fmaxf(cx, -1.0f), 1.0f);
    const float y01 = (cy + 1.0f) * 0.5f;
    const float x01 = (cx + 1.0f) * 0.5f;
    const float rr = 16.0f / 224.0f;
    const float step = (2.0f * rr) / 15.0f;
    const float* xb = x + (size_t)b * 3 * NPIX;

    for (int e = tid; e < 972; e += 256) {
        int c = e / 324, rem = e - c * 324;
        int yy = rem / 18, xx = rem - yy * 18;
        float val = 0.f;
        if (yy >= 1 && yy <= 16 && xx >= 1 && xx <= 16) {
            int i = yy - 1, j = xx - 1;
            float pj = (j == 15) ? rr : (-rr + (float)j * step);
            float pi = (i == 15) ? rr : (-rr + (float)i * step);
            // faithful bug: x-coordinate uses y01 (row), y-coordinate uses x01 (col)
            float gxn = (pj + y01) * 2.0f - 1.0f;
            float gyn = (pi + x01) * 2.0f - 1.0f;
            float gx = (gxn + 1.0f) * 0.5f * 223.0f;
            float gy = (gyn + 1.0f) * 0.5f * 223.0f;
            float x0 = floorf(gx), y0 = floorf(gy);
            float x1 = x0 + 1.0f, y1 = y0 + 1.0f;
            float wx1 = gx - x0, wy1 = gy - y0;
            float wx0 = 1.0f - wx1, wy0 = 1.0f - wy1;
            const float* img = xb + (size_t)c * NPIX;
            val = gat4(img, x0, y0) * (wx0 * wy0)
                + gat4(img, x1, y0) * (wx1 * wy0)
                + gat4(img, x0, y1) * (wx0 * wy1)
                + gat4(img, x1, y1) * (wx1 * wy1);
        }
        P[c][yy][xx] = val;
    }
    __syncthreads();

    const int i = tid >> 4, j = tid & 15;
    float acc[8];
    #pragma unroll
    for (int co = 0; co < 8; co++) acc[co] = conv_b[co];   // uniform -> s_load
    #pragma unroll
    for (int ci = 0; ci < 3; ci++) {
        float n[9];
        #pragma unroll
        for (int di = 0; di < 3; di++)
            #pragma unroll
            for (int dj = 0; dj < 3; dj++)
                n[di * 3 + dj] = P[ci][i + di][j + dj];
        #pragma unroll
        for (int co = 0; co < 8; co++) {
            float a = acc[co];
            #pragma unroll
            for (int u = 0; u < 9; u++)
                a += n[u] * conv_w[co * 27 + ci * 9 + u];  // uniform -> s_load
            acc[co] = a;
        }
    }
    const size_t mbase = ((size_t)(b * KP + s)) * 2048;
    #pragma unroll
    for (int co = 0; co < 8; co++)
        h[mbase + co * 256 + tid] = fmaxf(acc[co], 0.0f);
}

// ---------------------------------------------------------------------------
// K4: fc1 partial GEMM. grid (32 m-tiles, 16 k-slices) x 256.
// ---------------------------------------------------------------------------
__global__ __launch_bounds__(256) void k_fc1(
    const float* __restrict__ h, const float* __restrict__ fc1_w,
    float* __restrict__ partial) {
    const int mt = blockIdx.x;          // 0..31
    const int ks = blockIdx.y;          // 0..15
    const int tid = threadIdx.x;
    const int M0 = mt * 64;
    const int og = tid >> 4, mg = tid & 15;
    __shared__ float A[64 * 68];        // [k][m]
    __shared__ float W[64 * 68];        // [k][o]
    float acc[4][4];
    #pragma unroll
    for (int i = 0; i < 4; i++)
        #pragma unroll
        for (int j = 0; j < 4; j++) acc[i][j] = 0.f;

    #pragma unroll 1
    for (int ch = 0; ch < 2; ch++) {
        const int k0 = ks * 128 + ch * 64;
        __syncthreads();
        #pragma unroll
        for (int p = 0; p < 4; p++) {
            int row = p * 16 + (tid >> 4);      // 0..63
            int c0 = (tid & 15) * 4;            // k offset 0..60
            float4 av = *(const float4*)&h[(size_t)(M0 + row) * 2048 + k0 + c0];
            A[(c0 + 0) * 68 + row] = av.x;
            A[(c0 + 1) * 68 + row] = av.y;
            A[(c0 + 2) * 68 + row] = av.z;
            A[(c0 + 3) * 68 + row] = av.w;
            float4 wv = *(const float4*)&fc1_w[(size_t)row * 2048 + k0 + c0];
            W[(c0 + 0) * 68 + row] = wv.x;
            W[(c0 + 1) * 68 + row] = wv.y;
            W[(c0 + 2) * 68 + row] = wv.z;
            W[(c0 + 3) * 68 + row] = wv.w;
        }
        __syncthreads();
        #pragma unroll 4
        for (int k = 0; k < 64; k++) {
            float4 a = *(float4*)&A[k * 68 + mg * 4];
            float4 w = *(float4*)&W[k * 68 + og * 4];
            acc[0][0] += a.x * w.x; acc[0][1] += a.x * w.y;
            acc[0][2] += a.x * w.z; acc[0][3] += a.x * w.w;
            acc[1][0] += a.y * w.x; acc[1][1] += a.y * w.y;
            acc[1][2] += a.y * w.z; acc[1][3] += a.y * w.w;
            acc[2][0] += a.z * w.x; acc[2][1] += a.z * w.y;
            acc[2][2] += a.z * w.z; acc[2][3] += a.z * w.w;
            acc[3][0] += a.w * w.x; acc[3][1] += a.w * w.y;
            acc[3][2] += a.w * w.z; acc[3][3] += a.w * w.w;
        }
    }
    float* pb = partial + ((size_t)ks * 2048 + M0) * 64;
    #pragma unroll
    for (int mi = 0; mi < 4; mi++) {
        float4 v = make_float4(acc[mi][0], acc[mi][1], acc[mi][2], acc[mi][3]);
        *(float4*)&pb[(mg * 4 + mi) * 64 + og * 4] = v;
    }
}

// Sum 16 partials + bias + relu -> feat[b][4096] (coalesced identity store);
// also seed out[b][c] = fc2_b[c] (fc2 atomically accumulates later).
__global__ __launch_bounds__(256) void k_fc1_post(
    const float* __restrict__ partial, const float* __restrict__ fc1_b,
    const float* __restrict__ fc2_b, float* __restrict__ feat,
    float* __restrict__ out) {
    const int id = blockIdx.x * 256 + threadIdx.x;   // 0..131071
    const int o = id & 63;
    float s = 0.f;
    #pragma unroll
    for (int ks = 0; ks < FC1_KS; ks++) s += partial[(size_t)ks * 131072 + id];
    s = fmaxf(s + fc1_b[o], 0.f);
    feat[id] = s;                                    // [b][k] layout
    if (id < BATCH * NCLS) out[id] = fc2_b[id % NCLS];
}

// ---------------------------------------------------------------------------
// K5: fc2 out[b][c] += sum_k feat[b][k]*fc2_w[c][k], K split 16 ways.
// LDS-staged F2/Wc, grid (125,16).
// ---------------------------------------------------------------------------
__global__ __launch_bounds__(256) void k_fc2(
    const float* __restrict__ feat, const float* __restrict__ fc2_w,
    float* __restrict__ out) {
    const int c0 = blockIdx.x * 8;
    const int kbase = blockIdx.y * 256;
    const int tid = threadIdx.x;
    const int bq = tid & 7, kg = tid >> 3;          // b4 = bq*4; kg 0..31

    __shared__ float U[8192];                       // 32 KB union
    float* F2 = U;                                  // [32][132]
    float* Wc = U + 32 * 132;                       // [8][128]
    float* Red = U;                                 // [32][8][32] (aliased)

    float4 acc[8];
    #pragma unroll
    for (int cl = 0; cl < 8; cl++) acc[cl] = make_float4(0.f, 0.f, 0.f, 0.f);

    #pragma unroll 1
    for (int ch = 0; ch < 2; ch++) {
        const int k0 = kbase + ch * 128;
        __syncthreads();
        #pragma unroll
        for (int it = 0; it < 4; it++) {
            int l = it * 256 + tid;
            int bb = l >> 5, kc = (l & 31) << 2;
            *(float4*)&F2[bb * 132 + kc] =
                *(const float4*)&feat[(size_t)bb * 4096 + k0 + kc];
        }
        {
            int cl = tid >> 5, kc = (tid & 31) << 2;
            *(float4*)&Wc[cl * 128 + kc] =
                *(const float4*)&fc2_w[(size_t)(c0 + cl) * 4096 + k0 + kc];
        }
        __syncthreads();
        float4 f0 = *(float4*)&F2[(bq * 4 + 0) * 132 + kg * 4];
        float4 f1 = *(float4*)&F2[(bq * 4 + 1) * 132 + kg * 4];
        float4 f2 = *(float4*)&F2[(bq * 4 + 2) * 132 + kg * 4];
        float4 f3 = *(float4*)&F2[(bq * 4 + 3) * 132 + kg * 4];
        #pragma unroll
        for (int cl = 0; cl < 8; cl++) {
            float4 w = *(float4*)&Wc[cl * 128 + kg * 4];
            acc[cl].x += w.x * f0.x + w.y * f0.y + w.z * f0.z + w.w * f0.w;
            acc[cl].y += w.x * f1.x + w.y * f1.y + w.z * f1.z + w.w * f1.w;
            acc[cl].z += w.x * f2.x + w.y * f2.y + w.z * f2.z + w.w * f2.w;
            acc[cl].w += w.x * f3.x + w.y * f3.y + w.z * f3.z + w.w * f3.w;
        }
    }

    __syncthreads();   // all F2/Wc reads done before Red aliases the memory
    #pragma unroll
    for (int cl = 0; cl < 8; cl++)
        *(float4*)&Red[kg * 256 + cl * 32 + bq * 4] = acc[cl];
    __syncthreads();

    const int cl2 = tid >> 5, b2 = tid & 31;
    float s = 0.f;
    #pragma unroll
    for (int g = 0; g < 32; g++) s += Red[g * 256 + cl2 * 32 + b2];
    atomicAdd(&out[b2 * NCLS + c0 + cl2], s);
}

// ---------------------------------------------------------------------------
extern "C" void kernel_launch(void* const* d_in, const int* in_sizes, int n_in,
                              void* d_out, int out_size, void* d_ws, size_t ws_size,
                              hipStream_t stream) {
    const float* x      = (const float*)d_in[0];
    const float* conv_w = (const float*)d_in[1];
    const float* conv_b = (const float*)d_in[2];
    const float* fc1_w  = (const float*)d_in[3];
    const float* fc1_b  = (const float*)d_in[4];
    const float* fc2_w  = (const float*)d_in[5];
    const float* fc2_b  = (const float*)d_in[6];
    float* out = (float*)d_out;

    // ws layout. Region0 (8.39 MB): cand (459 KB) early, then reused as
    // fc1 partial[16][2048][64] — cand is dead before k_fc1 (stream-ordered).
    char* base = (char*)d_ws;
    const size_t region0 = (size_t)FC1_KS * 2048 * 64 * 4;       // 8.39 MB
    uint64_t* cand    = (uint64_t*)base;                         // 459 KB
    float*    partial = (float*)base;                            // alias
    float*    h       = (float*)(base + region0);                // 16.78 MB
    float*    feat    = h + (size_t)2048 * 2048;                 // 0.52 MB  [b][4096]
    int*      kp      = (int*)(feat + (size_t)4096 * 32);        // 8 KB

    k_harris_topk<<<dim3(28, 32), 256, 0, stream>>>(x, cand);
    k_topk_merge<<<32, 256, 0, stream>>>(cand, kp);
    k_patch_conv<<<dim3(KP, BATCH), 256, 0, stream>>>(x, kp, conv_w, conv_b, h);
    k_fc1<<<dim3(32, FC1_KS), 256, 0, stream>>>(h, fc1_w, partial);
    k_fc1_post<<<512, 256, 0, stream>>>(partial, fc1_b, fc2_b, feat, out);
    k_fc2<<<dim3(125, 16), 256, 0, stream>>>(feat, fc2_w, out);
}